// Round 1
// baseline (3078.998 us; speedup 1.0000x reference)
//
#include <hip/hip_runtime.h>
#include <math.h>

#define NL   16
#define DIM  1024
#define NH   16
#define NKV  8
#define DHD  128
#define SEQ  4096
#define FF   4096
#define VOC  32000
#define NS   32     // attention position splits

// workspace float offsets
#define XOFF   0         // x[1024]
#define NOFF   1024      // n[1024]
#define QOFF   2048      // q[2048] (roped in place)
#define KOFF   4096      // k pre-rope [1024]
#define VOFF   5120      // v [1024]
#define KCUR   6144      // roped k per layer [16*1024]
#define VCUR   22528     // v per layer [16*1024]
#define PMOFF  38912     // attn partial max [16*NS]
#define PLOFF  39424     // attn partial sum [16*NS]
#define POOFF  39936     // attn partial out [16*NS*128]
#define AOOFF  105472    // attn output [2048]
#define GUOFF  107520    // g[4096] u[4096]
#define LOGOFF 115712    // logits[32000]

__global__ __launch_bounds__(256) void zero_logits_k(float* ws) {
    int c4 = blockIdx.x * 256 + threadIdx.x;
    if (c4 < VOC / 4) ((float4*)(ws + LOGOFF))[c4] = make_float4(0.f, 0.f, 0.f, 0.f);
}

__global__ __launch_bounds__(256) void init_x_k(const float* __restrict__ embed,
                                                const int* __restrict__ ids, float* ws) {
    int t = threadIdx.x;
    int tok = ids[0];
    ((float4*)(ws + XOFF))[t] = ((const float4*)(embed + (size_t)tok * DIM))[t];
}

// rmsnorm over 1024 elems (1 block, 256 thr) + zero a scratch region (zc4 float4s)
__global__ __launch_bounds__(256) void rmsnorm_zero_k(const float* __restrict__ x,
                                                      const float* __restrict__ w,
                                                      float* __restrict__ n,
                                                      float* __restrict__ z, int zc4) {
    __shared__ float red[256];
    int t = threadIdx.x;
    float4 xv = ((const float4*)x)[t];
    red[t] = xv.x * xv.x + xv.y * xv.y + xv.z * xv.z + xv.w * xv.w;
    __syncthreads();
    for (int s = 128; s > 0; s >>= 1) {
        if (t < s) red[t] += red[t + s];
        __syncthreads();
    }
    float r = rsqrtf(red[0] * (1.0f / DIM) + 1e-6f);
    float4 wv = ((const float4*)w)[t];
    float4 o;
    o.x = xv.x * r * wv.x; o.y = xv.y * r * wv.y;
    o.z = xv.z * r * wv.z; o.w = xv.w * r * wv.w;
    ((float4*)n)[t] = o;
    float4 zz = make_float4(0.f, 0.f, 0.f, 0.f);
    for (int j = t; j < zc4; j += 256) ((float4*)z)[j] = zz;
}

// fused q/k/v matvec: out[0:2048]=n@Wq, [2048:3072]=n@Wk, [3072:4096]=n@Wv
// grid (4, 32), 32 rows per chunk, atomicAdd accumulate
__global__ __launch_bounds__(256) void matvec_qkv_k(const float* __restrict__ Wq,
                                                    const float* __restrict__ Wk,
                                                    const float* __restrict__ Wv,
                                                    const float* __restrict__ xin,
                                                    float* __restrict__ out) {
    int c4 = blockIdx.x * 256 + threadIdx.x;  // [0,1024) float4 cols
    const float4* W4; int st4, cc;
    if (c4 < 512)      { W4 = (const float4*)Wq; st4 = 512; cc = c4; }
    else if (c4 < 768) { W4 = (const float4*)Wk; st4 = 256; cc = c4 - 512; }
    else               { W4 = (const float4*)Wv; st4 = 256; cc = c4 - 768; }
    int r0 = blockIdx.y * 32;
    float4 acc = make_float4(0.f, 0.f, 0.f, 0.f);
    for (int r = r0; r < r0 + 32; ++r) {
        float xv = xin[r];
        float4 w = W4[(size_t)r * st4 + cc];
        acc.x += xv * w.x; acc.y += xv * w.y; acc.z += xv * w.z; acc.w += xv * w.w;
    }
    float* o = out + 4 * (size_t)c4;
    atomicAdd(o + 0, acc.x); atomicAdd(o + 1, acc.y);
    atomicAdd(o + 2, acc.z); atomicAdd(o + 3, acc.w);
}

// fused gate/up matvec: out[0:4096]=n@Wg, [4096:8192]=n@Wu. grid (8,16), 64 rows/chunk
__global__ __launch_bounds__(256) void matvec_gu_k(const float* __restrict__ Wg,
                                                   const float* __restrict__ Wu,
                                                   const float* __restrict__ xin,
                                                   float* __restrict__ out) {
    int c4 = blockIdx.x * 256 + threadIdx.x;  // [0,2048)
    const float4* W4; int cc;
    if (c4 < 1024) { W4 = (const float4*)Wg; cc = c4; }
    else           { W4 = (const float4*)Wu; cc = c4 - 1024; }
    int r0 = blockIdx.y * 64;
    float4 acc = make_float4(0.f, 0.f, 0.f, 0.f);
    for (int r = r0; r < r0 + 64; ++r) {
        float xv = xin[r];
        float4 w = W4[(size_t)r * 1024 + cc];
        acc.x += xv * w.x; acc.y += xv * w.y; acc.z += xv * w.z; acc.w += xv * w.w;
    }
    float* o = out + 4 * (size_t)c4;
    atomicAdd(o + 0, acc.x); atomicAdd(o + 1, acc.y);
    atomicAdd(o + 2, acc.z); atomicAdd(o + 3, acc.w);
}

// generic matvec with atomic accumulate. grid (ceil(dout4/256), nchunks), rc rows/chunk
__global__ __launch_bounds__(256) void matvec_plain_k(const float* __restrict__ W,
                                                      const float* __restrict__ xin,
                                                      float* __restrict__ out,
                                                      int dout4, int rc) {
    int c4 = blockIdx.x * 256 + threadIdx.x;
    if (c4 >= dout4) return;
    int r0 = blockIdx.y * rc;
    const float4* W4 = (const float4*)W;
    float4 acc = make_float4(0.f, 0.f, 0.f, 0.f);
    for (int r = r0; r < r0 + rc; ++r) {
        float xv = xin[r];
        float4 w = W4[(size_t)r * dout4 + c4];
        acc.x += xv * w.x; acc.y += xv * w.y; acc.z += xv * w.z; acc.w += xv * w.w;
    }
    float* o = out + 4 * (size_t)c4;
    atomicAdd(o + 0, acc.x); atomicAdd(o + 1, acc.y);
    atomicAdd(o + 2, acc.z); atomicAdd(o + 3, acc.w);
}

// down-proj with silu(g)*u computed on the fly; accumulates into x. grid (1,128), 32 rows
__global__ __launch_bounds__(256) void matvec_wd_k(const float* __restrict__ Wd,
                                                   const float* __restrict__ gu,
                                                   float* __restrict__ xout) {
    int c4 = threadIdx.x;  // 256 float4 = 1024 cols
    int r0 = blockIdx.y * 32;
    const float4* W4 = (const float4*)Wd;
    float4 acc = make_float4(0.f, 0.f, 0.f, 0.f);
    for (int r = r0; r < r0 + 32; ++r) {
        float g = gu[r], u = gu[FF + r];
        float xv = (g / (1.0f + __expf(-g))) * u;
        float4 w = W4[(size_t)r * 256 + c4];
        acc.x += xv * w.x; acc.y += xv * w.y; acc.z += xv * w.z; acc.w += xv * w.w;
    }
    float* o = xout + 4 * (size_t)c4;
    atomicAdd(o + 0, acc.x); atomicAdd(o + 1, acc.y);
    atomicAdd(o + 2, acc.z); atomicAdd(o + 3, acc.w);
}

// rope q (in place) and k (KOFF -> KCUR[l]); copy v (VOFF -> VCUR[l]). 1 block.
__global__ __launch_bounds__(256) void rope_cache_k(float* ws, const int* __restrict__ step,
                                                    const int* __restrict__ prefill, int l) {
    int pos = prefill[0] + step[0];
    float fpos = (float)pos;
    const int NPAIR = (NH + NKV) * 64;  // 1536
    for (int t = threadIdx.x; t < NPAIR + NKV * DHD; t += 256) {
        if (t < NPAIR) {
            int head = t >> 6, i = t & 63;
            // inv_freq = 10000^(-2i/128)
            float inv = expf(-(2.0f * (float)i) * (1.0f / DHD) * 9.210340371976184f);
            float ang = fpos * inv;
            float c = cosf(ang), s = sinf(ang);
            const float* src; float* dst;
            if (head < NH) { src = ws + QOFF + head * DHD; dst = ws + QOFF + head * DHD; }
            else {
                int kvh = head - NH;
                src = ws + KOFF + kvh * DHD;
                dst = ws + KCUR + l * NKV * DHD + kvh * DHD;
            }
            float x1 = src[i], x2 = src[i + 64];
            dst[i] = x1 * c - x2 * s;
            dst[i + 64] = x2 * c + x1 * s;
        } else {
            int j = t - NPAIR;
            ws[VCUR + l * NKV * DHD + j] = ws[VOFF + j];
        }
    }
}

// flash-decode partials: grid (NH, NS), 256 thr (4 waves), online softmax per wave
__global__ __launch_bounds__(256) void attn_partial_k(const float* __restrict__ PK,
                                                      const float* __restrict__ PV,
                                                      float* ws,
                                                      const int* __restrict__ step,
                                                      const int* __restrict__ prefill, int l) {
    int h = blockIdx.x, split = blockIdx.y;
    int pos = prefill[0] + step[0];
    int total = pos + 1;
    int kv = h >> 1;  // rep = 2
    int lane = threadIdx.x & 63, wave = threadIdx.x >> 6;
    float2 qv = ((const float2*)(ws + QOFF + h * DHD))[lane];
    const int chunk = SEQ / NS;  // 128
    int s0 = split * chunk;
    int s1 = min(s0 + chunk, total);
    size_t kvoff = ((size_t)l * NKV + kv) * (size_t)SEQ * DHD;
    const float* Kb = PK + kvoff;
    const float* Vb = PV + kvoff;
    const float* kc = ws + KCUR + (l * NKV + kv) * DHD;
    const float* vc = ws + VCUR + (l * NKV + kv) * DHD;
    float m = -1e30f, lsum = 0.f;
    float2 acc = make_float2(0.f, 0.f);
    for (int s = s0 + wave; s < s1; s += 4) {
        const float* kr = (s == pos) ? kc : (Kb + (size_t)s * DHD);
        float2 kk = ((const float2*)kr)[lane];
        float d = qv.x * kk.x + qv.y * kk.y;
#pragma unroll
        for (int off = 32; off > 0; off >>= 1) d += __shfl_xor(d, off, 64);
        d *= 0.08838834764831845f;  // 1/sqrt(128)
        float mn = fmaxf(m, d);
        float fw = __expf(m - mn);
        float w = __expf(d - mn);
        const float* vr = (s == pos) ? vc : (Vb + (size_t)s * DHD);
        float2 vv = ((const float2*)vr)[lane];
        acc.x = acc.x * fw + w * vv.x;
        acc.y = acc.y * fw + w * vv.y;
        lsum = lsum * fw + w;
        m = mn;
    }
    __shared__ float sm[4], sl[4], so[4][128];
    if (lane == 0) { sm[wave] = m; sl[wave] = lsum; }
    so[wave][2 * lane] = acc.x;
    so[wave][2 * lane + 1] = acc.y;
    __syncthreads();
    if (wave == 0) {
        float M = fmaxf(fmaxf(sm[0], sm[1]), fmaxf(sm[2], sm[3]));
        float Lt = 0.f, ox = 0.f, oy = 0.f;
#pragma unroll
        for (int i = 0; i < 4; ++i) {
            float wi = __expf(sm[i] - M);
            Lt += sl[i] * wi;
            ox += so[i][2 * lane] * wi;
            oy += so[i][2 * lane + 1] * wi;
        }
        int p = h * NS + split;
        if (lane == 0) { ws[PMOFF + p] = M; ws[PLOFF + p] = Lt; }
        ((float2*)(ws + POOFF + (size_t)p * DHD))[lane] = make_float2(ox, oy);
    }
}

// combine NS partials per head -> attn out. grid (NH), 128 thr
__global__ __launch_bounds__(128) void attn_combine_k(float* ws) {
    int h = blockIdx.x, d = threadIdx.x;
    float M = -1e30f;
    for (int i = 0; i < NS; ++i) M = fmaxf(M, ws[PMOFF + h * NS + i]);
    float den = 0.f, num = 0.f;
    for (int i = 0; i < NS; ++i) {
        float wi = __expf(ws[PMOFF + h * NS + i] - M);
        den += ws[PLOFF + h * NS + i] * wi;
        num += ws[POOFF + (size_t)(h * NS + i) * DHD + d] * wi;
    }
    ws[AOOFF + h * DHD + d] = num / den;
}

__global__ __launch_bounds__(256) void argmax_k(const float* __restrict__ logits, float* out) {
    __shared__ float sv[256];
    __shared__ int si[256];
    int t = threadIdx.x;
    float best = -3.4e38f; int bi = 0x7fffffff;
    for (int j = t; j < VOC; j += 256) {
        float v = logits[j];
        if (v > best) { best = v; bi = j; }
    }
    sv[t] = best; si[t] = bi;
    __syncthreads();
    for (int s = 128; s > 0; s >>= 1) {
        if (t < s) {
            if (sv[t + s] > sv[t] || (sv[t + s] == sv[t] && si[t + s] < si[t])) {
                sv[t] = sv[t + s]; si[t] = si[t + s];
            }
        }
        __syncthreads();
    }
    if (t == 0) out[0] = (float)si[0];
}

// copy both caches to d_out (misaligned by 1 float -> scalar dwords), substituting
// the new (roped) k / v column at s == pos from workspace
__global__ __launch_bounds__(256) void cache_copy_k(const float* __restrict__ PK,
                                                    const float* __restrict__ PV,
                                                    const float* __restrict__ ws,
                                                    const int* __restrict__ step,
                                                    const int* __restrict__ prefill,
                                                    float* __restrict__ out) {
    int pos = prefill[0] + step[0];
    const int N = NL * NKV * SEQ * DHD;  // 67108864
    const int stride = 8192 * 256;
    for (int idx = blockIdx.x * 256 + threadIdx.x; idx < 2 * N; idx += stride) {
        int isV = idx >= N;
        int j = isV ? idx - N : idx;
        int s = (j >> 7) & (SEQ - 1);
        float val;
        if (s == pos) {
            int dd = j & 127;
            int lkv = j >> 19;  // l*NKV + kv, since S*Dh = 2^19
            val = ws[(isV ? VCUR : KCUR) + lkv * DHD + dd];
        } else {
            val = (isV ? PV : PK)[j];
        }
        out[idx] = val;
    }
}

extern "C" void kernel_launch(void* const* d_in, const int* in_sizes, int n_in,
                              void* d_out, int out_size, void* d_ws, size_t ws_size,
                              hipStream_t stream) {
    const int*   input_ids = (const int*)d_in[0];
    const int*   step      = (const int*)d_in[1];
    const int*   prefill   = (const int*)d_in[2];
    const float* past_keys = (const float*)d_in[3];
    const float* past_vals = (const float*)d_in[4];
    const float* embed     = (const float*)d_in[5];
    const float* Wq        = (const float*)d_in[6];
    const float* Wk        = (const float*)d_in[7];
    const float* Wv        = (const float*)d_in[8];
    const float* Wo        = (const float*)d_in[9];
    const float* Wg        = (const float*)d_in[10];
    const float* Wu        = (const float*)d_in[11];
    const float* Wd        = (const float*)d_in[12];
    const float* ln1       = (const float*)d_in[13];
    const float* ln2       = (const float*)d_in[14];
    const float* lnf       = (const float*)d_in[15];
    const float* Wlm       = (const float*)d_in[16];
    float* out = (float*)d_out;
    float* ws  = (float*)d_ws;

    zero_logits_k<<<32, 256, 0, stream>>>(ws);
    init_x_k<<<1, 256, 0, stream>>>(embed, input_ids, ws);

    for (int l = 0; l < NL; ++l) {
        rmsnorm_zero_k<<<1, 256, 0, stream>>>(ws + XOFF, ln1 + (size_t)l * DIM,
                                              ws + NOFF, ws + QOFF, 1024);
        matvec_qkv_k<<<dim3(4, 32), 256, 0, stream>>>(
            Wq + (size_t)l * DIM * 2048, Wk + (size_t)l * DIM * 1024,
            Wv + (size_t)l * DIM * 1024, ws + NOFF, ws + QOFF);
        rope_cache_k<<<1, 256, 0, stream>>>(ws, step, prefill, l);
        attn_partial_k<<<dim3(NH, NS), 256, 0, stream>>>(past_keys, past_vals, ws,
                                                         step, prefill, l);
        attn_combine_k<<<NH, 128, 0, stream>>>(ws);
        matvec_plain_k<<<dim3(1, 128), 256, 0, stream>>>(
            Wo + (size_t)l * 2048 * 1024, ws + AOOFF, ws + XOFF, 256, 16);
        rmsnorm_zero_k<<<1, 256, 0, stream>>>(ws + XOFF, ln2 + (size_t)l * DIM,
                                              ws + NOFF, ws + GUOFF, 2048);
        matvec_gu_k<<<dim3(8, 16), 256, 0, stream>>>(
            Wg + (size_t)l * DIM * FF, Wu + (size_t)l * DIM * FF, ws + NOFF, ws + GUOFF);
        matvec_wd_k<<<dim3(1, 128), 256, 0, stream>>>(
            Wd + (size_t)l * FF * DIM, ws + GUOFF, ws + XOFF);
    }

    rmsnorm_zero_k<<<1, 256, 0, stream>>>(ws + XOFF, lnf, ws + NOFF, ws + LOGOFF, 0);
    matvec_plain_k<<<dim3(32, 8), 256, 0, stream>>>(Wlm, ws + NOFF, ws + LOGOFF, 8000, 128);
    argmax_k<<<1, 256, 0, stream>>>(ws + LOGOFF, out);
    cache_copy_k<<<8192, 256, 0, stream>>>(past_keys, past_vals, ws, step, prefill, out + 1);
}